// Round 3
// baseline (803.683 us; speedup 1.0000x reference)
//
#include <hip/hip_runtime.h>

// SequentialChart: ops < START(256) => steps independent. Algebraic cut:
// PL[b,op]=U_left@h(b,op), PR[b,op]=U_right@h(b,op) (16x fewer FLOPs),
// preact = PL[opL]+PR[opR] (bias folded into PL at GEMM epilogue).
// log2e folded into U/bias at cvt time: gates use raw v_exp_f32 (exp2).
// GEMM: persistent 256-block kernel; each block chains 5 tiles (256x256,
// BK=64, 8-wave 8-phase double-buffered pipeline) through ONE pipeline that
// never drains: it=7 prefetches target the next tile's K-steps 0/1.
// Counted vmcnt(4) at phases 4/8; vmcnt(0) only once at block end.
// Fused gates+softmax+combine: c in 64KB LDS, h in packed-bf16 regs,
// cross-wave h-reduction through reused LDS -> 2 blocks/CU.

typedef unsigned int u32;
typedef unsigned short u16;
typedef __attribute__((ext_vector_type(8))) short short8;
typedef __attribute__((ext_vector_type(4))) float f32x4;
typedef __attribute__((ext_vector_type(4))) u16 u16x4;
typedef __attribute__((ext_vector_type(8))) u16 u16x8;
typedef _Float16 h8 __attribute__((ext_vector_type(8)));

#define CHART_ROWS 384
#define L2E 1.4426950408889634f

__device__ __forceinline__ u16 f2bf(float f) {           // fp32 -> bf16 RNE
  u32 u = __float_as_uint(f);
  u32 r = u + 0x7fffu + ((u >> 16) & 1u);
  return (u16)(r >> 16);
}
__device__ __forceinline__ float bf2f(u16 v) { return __uint_as_float(((u32)v) << 16); }
// preact pre-scaled by -log2e: sigmoid(x) = 1/(1+2^(-x*log2e))
__device__ __forceinline__ float sig2(float p) {
  return __builtin_amdgcn_rcpf(1.0f + __builtin_amdgcn_exp2f(p));
}
// preact pre-scaled by +2*log2e: tanh(x) = 1 - 2/(1+2^(2x*log2e))
__device__ __forceinline__ float tanh2(float p) {
  return 1.0f - 2.0f * __builtin_amdgcn_rcpf(1.0f + __builtin_amdgcn_exp2f(p));
}
// runtime-argument tanh (for tanh(c)); compiler folds 2*log2e into one mul
__device__ __forceinline__ float fast_tanh(float x) {
  return 1.0f - 2.0f * __builtin_amdgcn_rcpf(1.0f + __builtin_amdgcn_exp2f(2.0f * L2E * x));
}

__device__ __forceinline__ void async16(const void* g, void* l) {
  __builtin_amdgcn_global_load_lds((const __attribute__((address_space(1))) u32*)g,
                                   (__attribute__((address_space(3))) u32*)l, 16, 0, 0);
}

#define BAR() __builtin_amdgcn_s_barrier()
#define VMCNT4 asm volatile("s_waitcnt vmcnt(4)" ::: "memory")
#define VMCNT0 asm volatile("s_waitcnt vmcnt(0)" ::: "memory")

// ---- U (5120x2048 fp32) -> bf16, scaled by -log2e (sigmoid rows) / +2log2e (u rows)
__global__ void k_cvt_u(const float4* __restrict__ U4, u16* __restrict__ Ubf) {
  int i = blockIdx.x * blockDim.x + threadIdx.x;   // 2,621,440 threads
  int row = i >> 9;                                // 512 float4 per 2048-col row
  float sc = (row < 4096) ? -L2E : (2.0f * L2E);
  float4 v = U4[i];
  u16x4 o = {f2bf(v.x * sc), f2bf(v.y * sc), f2bf(v.z * sc), f2bf(v.w * sc)};
  *(u16x4*)(Ubf + (size_t)i * 4) = o;
}

// ---- chart rows<256: h-half -> chb, c-half -> chc; also copy rows<256 to out
__global__ void k_cvt_chart(const float* __restrict__ chart,
                            u16* __restrict__ chb, u16* __restrict__ chc,
                            float* __restrict__ out) {
  int i = blockIdx.x * blockDim.x + threadIdx.x;   // 2,097,152 threads
  int row = i >> 8;                 // b*256 + op, < 8192
  int k4 = (i & 255) * 4;
  int b = row >> 8, op = row & 255;
  const size_t base = (size_t)(b * CHART_ROWS + op) * 2048;
  const float4 vh = *(const float4*)(chart + base + 1024 + k4);
  const float4 vc = *(const float4*)(chart + base + k4);
  u16x4 oh = {f2bf(vh.x), f2bf(vh.y), f2bf(vh.z), f2bf(vh.w)};
  u16x4 oc = {f2bf(vc.x), f2bf(vc.y), f2bf(vc.z), f2bf(vc.w)};
  *(u16x4*)(chb + (size_t)row * 1024 + k4) = oh;
  *(u16x4*)(chc + (size_t)row * 1024 + k4) = oc;
  *(float4*)(out + base + k4) = vc;          // rows < 256 pass through
  *(float4*)(out + base + 1024 + k4) = vh;   // rows >= 256 written by k_fused
}

// ---- P[slab][2048 rows][5120] = chb-rows @ U-half (+bias*scale on half0)
// slab = bgl*2 + uhalf (bgl local to this dispatch). Persistent: block f
// chains tiles f, f+256, f+512, ... (tile id -> (bx, uhalf, bgl, mtile)).
#define LOAD_A(BUFO, MH) do { \
  _Pragma("unroll") \
  for (int i_ = 0; i_ < 4; ++i_) { \
    a[0][i_] = *(const short8*)(As + (BUFO) + am + (MH)*4096 + i_*1024 + sl0); \
    a[1][i_] = *(const short8*)(As + (BUFO) + am + (MH)*4096 + i_*1024 + sl1); \
  } } while (0)

#define LOAD_B(BUFO, NH, BR) do { \
  _Pragma("unroll") \
  for (int j_ = 0; j_ < 2; ++j_) { \
    BR[0][j_] = *(const short8*)(Bs + (BUFO) + bm + (NH)*2048 + j_*1024 + sl0); \
    BR[1][j_] = *(const short8*)(Bs + (BUFO) + bm + (NH)*2048 + j_*1024 + sl1); \
  } } while (0)

#define MFMA_Q(MH, NH, BR) do { \
  __builtin_amdgcn_s_setprio(1); \
  _Pragma("unroll") \
  for (int kk_ = 0; kk_ < 2; ++kk_) \
    _Pragma("unroll") \
    for (int i_ = 0; i_ < 4; ++i_) \
      _Pragma("unroll") \
      for (int j_ = 0; j_ < 2; ++j_) \
        acc[(MH)*4+i_][(NH)*2+j_] = __builtin_amdgcn_mfma_f32_16x16x32_bf16( \
            a[kk_][i_], BR[kk_][j_], acc[(MH)*4+i_][(NH)*2+j_], 0, 0, 0); \
  __builtin_amdgcn_s_setprio(0); } while (0)

__global__ __launch_bounds__(512, 2) void k_gemm_p(
    const u16* __restrict__ chb, const u16* __restrict__ Ubf,
    const float* __restrict__ bias, _Float16* __restrict__ P,
    int tile_count, int nbg, int bg0)
{
  __shared__ u16 As[2 * 256 * 64];   // 64 KB: two K-tile buffers (halves stacked)
  __shared__ u16 Bs[2 * 256 * 64];   // 64 KB

  const int tid = threadIdx.x;
  const int wid = tid >> 6, lane = tid & 63;
  const int lane15 = lane & 15, quad = lane >> 4;
  const int wr = wid >> 2, wc = wid & 3;

  // XCD-chunked block id (grid is always 256): XCD x gets 32 consecutive f.
  const int f = ((blockIdx.x & 7) << 5) | (blockIdx.x >> 3);
  const int NB = 256;
  if (f >= tile_count) return;
  const int nt = (tile_count - f + NB - 1) / NB;   // tiles chained by this block

  // tile id -> coordinates / staging bases
  const int perBx = nbg << 4;                      // tiles per bx group
  auto tcoord = [&](int tile, int& bx, int& uh, int& bgl, int& mt) {
    bx = tile / perBx;
    int rem = tile - bx * perBx;
    uh = (rem >= (nbg << 3)) ? 1 : 0;
    int rem2 = rem - uh * (nbg << 3);
    bgl = rem2 >> 3; mt = rem2 & 7;
  };
  auto tbases = [&](int tile, const u16*& Ab, const u16*& Bb) {
    int bx, uh, bgl, mt; tcoord(tile, bx, uh, bgl, mt);
    Ab = chb + (size_t)((bg0 + bgl) * 2048 + mt * 256) * 1024;
    Bb = Ubf + (size_t)bx * 524288 + (size_t)uh * 1024;
  };

  // per-thread staging offsets (swizzled source, linear LDS dest)
  // chunk idx = rnd*512+tid: row r=idx>>3 (0..127), slot s=idx&7, src chunk c=s^(r&7)
  int aoff[2], boff[2], dOff[2];
#pragma unroll
  for (int rnd = 0; rnd < 2; ++rnd) {
    int idx = rnd * 512 + tid;
    int r = idx >> 3, s = idx & 7, c = s ^ (r & 7);
    aoff[rnd] = r * 1024 + c * 8;
    boff[rnd] = r * 2048 + c * 8;
    dOff[rnd] = idx * 8;                   // u16 units
  }
  auto SA = [&](int buf, int h, int T, const u16* base) {
#pragma unroll
    for (int rnd = 0; rnd < 2; ++rnd)
      async16(base + aoff[rnd] + h * 131072 + T * 64,
              As + buf * 16384 + h * 8192 + dOff[rnd]);
  };
  auto SB = [&](int buf, int h, int T, const u16* base) {
#pragma unroll
    for (int rnd = 0; rnd < 2; ++rnd)
      async16(base + boff[rnd] + h * 262144 + T * 64,
              Bs + buf * 16384 + h * 8192 + dOff[rnd]);
  };

  // fragment read bases; frag row & 7 == lane15 & 7 (all tile offsets mult of 8)
  const int sl0 = ((0 * 4 + quad) ^ (lane15 & 7)) * 8;   // kk=0 slot
  const int sl1 = ((1 * 4 + quad) ^ (lane15 & 7)) * 8;   // kk=1 slot
  const int am = (wr * 128 + lane15) * 64;   // + mh*4096 + i*1024
  const int bm = (wc * 64 + lane15) * 64;    // + nh*2048 + j*1024

  f32x4 acc[8][4];
#pragma unroll
  for (int m_ = 0; m_ < 8; ++m_)
#pragma unroll
    for (int n_ = 0; n_ < 4; ++n_) acc[m_][n_] = (f32x4){0.f, 0.f, 0.f, 0.f};

  short8 a[2][4], b0r[2][2], b1r[2][2];

  const u16 *AbC, *BbC, *AbN, *BbN;
  tbases(f, AbC, BbC);
  if (nt > 1) tbases(f + NB, AbN, BbN); else { AbN = AbC; BbN = BbC; }

  // prologue: tile0 K-step0 fully + K-step1 B-halves (A of step1 staged in it0)
  SB(0, 0, 0, BbC); SB(0, 1, 0, BbC); SA(0, 0, 0, AbC); SA(0, 1, 0, AbC);
  SB(1, 0, 1, BbC); SB(1, 1, 1, BbC);
  VMCNT4;                                  // step0 landed (step1-B in flight)
  BAR();

  for (int t = 0; t < nt; ++t) {
    const bool hn = (t + 1 < nt);
    for (int it = 0; it < 8; ++it) {
      const bool cx = (it == 7);                 // T2/T3 cross into next tile
      const int T1 = 2 * it + 1;
      const int T2 = cx ? 0 : 2 * it + 2;
      const int T3 = cx ? 1 : 2 * it + 3;
      const u16* a2 = cx ? AbN : AbC;
      const u16* b2 = cx ? BbN : BbC;
      const bool s23 = !cx || hn;                // do the T2/T3 stages?
      // ---- phases 1-4: even K-step from buf0 ----
      LOAD_A(0, 0); LOAD_B(0, 0, b0r);
      SA(1, 0, T1, AbC);
      BAR(); MFMA_Q(0, 0, b0r); BAR();

      LOAD_B(0, 1, b1r);
      SA(1, 1, T1, AbC);
      BAR(); MFMA_Q(0, 1, b1r); BAR();

      LOAD_A(0, 1);
      if (s23) SB(0, 0, T2, b2);                 // buf0 B free after phase 2
      BAR(); MFMA_Q(1, 0, b0r); BAR();

      if (s23) SB(0, 1, T2, b2);
      BAR(); MFMA_Q(1, 1, b1r);
      if (cx && !hn) { VMCNT0; } else { VMCNT4; }   // odd K-step fully landed
      BAR();
      // ---- phases 5-8: odd K-step from buf1 ----
      LOAD_A(16384, 0); LOAD_B(16384, 0, b0r);
      if (s23) SA(0, 0, T2, a2);                 // buf0 A free after phase 3
      BAR(); MFMA_Q(0, 0, b0r); BAR();

      LOAD_B(16384, 1, b1r);
      if (s23) SA(0, 1, T2, a2);
      BAR(); MFMA_Q(0, 1, b1r); BAR();

      LOAD_A(16384, 1);
      if (s23) SB(1, 0, T3, b2);                 // buf1 B free after phase 6
      BAR(); MFMA_Q(1, 0, b0r); BAR();

      if (s23) SB(1, 1, T3, b2);
      BAR(); MFMA_Q(1, 1, b1r);
      if (s23) VMCNT4;                           // next even K-step landed
      BAR();
    }

    // epilogue for tile f + t*NB: bias + fp16 store + acc re-zero.
    // Per-wave only (no barrier, no LDS) -> overlaps next tile's pipeline.
    {
      int tile = f + t * NB;
      int bx, uh, bgl, mt; tcoord(tile, bx, uh, bgl, mt);
      float bb[4];
#pragma unroll
      for (int n_ = 0; n_ < 4; ++n_) {
        int g = bx * 256 + wc * 64 + n_ * 16 + lane15;
        float sc = (g < 4096) ? -L2E : (2.0f * L2E);
        bb[n_] = (uh == 0) ? bias[g] * sc : 0.f;
      }
      _Float16* Pb = P + ((size_t)((bgl * 2 + uh) * 2048 + mt * 256 + wr * 128)) * 5120
                   + bx * 256 + wc * 64;
#pragma unroll
      for (int m_ = 0; m_ < 8; ++m_)
#pragma unroll
        for (int rg = 0; rg < 4; ++rg) {
          _Float16* pr = Pb + (size_t)(m_ * 16 + quad * 4 + rg) * 5120;
#pragma unroll
          for (int n_ = 0; n_ < 4; ++n_)
            pr[n_ * 16 + lane15] = (_Float16)(acc[m_][n_][rg] + bb[n_]);
        }
#pragma unroll
      for (int m_ = 0; m_ < 8; ++m_)
#pragma unroll
        for (int n_ = 0; n_ < 4; ++n_) acc[m_][n_] = (f32x4){0.f, 0.f, 0.f, 0.f};
    }
    AbC = AbN; BbC = BbN;
    if (t + 2 < nt) tbases(f + (t + 2) * NB, AbN, BbN);
  }
}

// ---- fused: gather-add preact + gates + energy + softmax + combine ----
// Pl = base of this bg's half0 P-slab; half1 slab follows at +2048*5120.
__global__ __launch_bounds__(512, 4) void k_fused(
    const u16* __restrict__ chc, const _Float16* __restrict__ Pl,
    const int* __restrict__ ops, const float* __restrict__ eu,
    float* __restrict__ out, int bg)
{
  __shared__ u16 cS[32 * 1024];   // 64 KB; reused as float[8*1024] for h-reduce
  __shared__ float eS[32];

  const int tid = threadIdx.x;
  const int wave = tid >> 6, lane = tid & 63;
  const int flat = blockIdx.x;
  const int b_local = flat & 7;     // XCD-affine: same-XCD blocks share b
  const int step = flat >> 3;
  const int b = bg * 8 + b_local;

  float ureg[16];
  *(float4*)&ureg[0]  = *(const float4*)(eu + lane * 16);
  *(float4*)&ureg[4]  = *(const float4*)(eu + lane * 16 + 4);
  *(float4*)&ureg[8]  = *(const float4*)(eu + lane * 16 + 8);
  *(float4*)&ureg[12] = *(const float4*)(eu + lane * 16 + 12);
  float part = 0.f;
#pragma unroll
  for (int j = 0; j < 16; ++j) part += ureg[j] * ureg[j];
#pragma unroll
  for (int m = 1; m < 64; m <<= 1) part += __shfl_xor(part, m, 64);
  const float unorm = fmaxf(sqrtf(part), 1e-8f);

  u32 hPk[32];    // packed bf16 h: hPk[t*8 + sub*4 + (j>>1)] = cols (jj, jj+1)

  for (int t = 0; t < 4; ++t) {
    const int a = t * 8 + wave;
    const long opflat = (((long)step * 32 + b) * 32 + a) * 2;
    const int opL = ops[opflat], opR = ops[opflat + 1];
    const _Float16* PLp = Pl + (size_t)(b_local * 256 + opL) * 5120;
    const _Float16* PRp = Pl + ((size_t)2048 * 5120 + (size_t)(b_local * 256 + opR) * 5120);
    const u16* ccLr = chc + (size_t)(b * 256 + opL) * 1024;
    const u16* ccRr = chc + (size_t)(b * 256 + opR) * 1024;
    float dot = 0.f, nn = 0.f;
#pragma unroll
    for (int sub = 0; sub < 2; ++sub) {
      const int g8 = lane * 16 + sub * 8;
      h8 pre[5];
#pragma unroll
      for (int q = 0; q < 5; ++q)
        pre[q] = *(const h8*)(PLp + q * 1024 + g8) + *(const h8*)(PRp + q * 1024 + g8);
      const u16x8 cl = *(const u16x8*)(ccLr + g8);
      const u16x8 cr = *(const u16x8*)(ccRr + g8);
      u16x8 co;
      u32 lo = 0;
#pragma unroll
      for (int j = 0; j < 8; ++j) {
        const int jj = sub * 8 + j;
        float pi  = (float)pre[0][j];   // pre-scaled by -log2e
        float pfL = (float)pre[1][j];
        float pfR = (float)pre[2][j];
        float po  = (float)pre[3][j];
        float pu  = (float)pre[4][j];   // pre-scaled by +2*log2e
        float cv = sig2(pfL) * bf2f(cl[j]) + sig2(pfR) * bf2f(cr[j])
                 + sig2(pi) * tanh2(pu);
        float hv = sig2(po) * fast_tanh(cv);
        co[j] = f2bf(cv);
        if ((j & 1) == 0) lo = (u32)f2bf(hv);
        else hPk[t * 8 + sub * 4 + (j >> 1)] = lo | ((u32)f2bf(hv) << 16);
        dot += hv * ureg[jj];
        nn  += hv * hv;
      }
      *(u16x8*)(cS + a * 1024 + sub * 512 + lane * 8) = co;  // permuted, b128
    }
#pragma unroll
    for (int m = 1; m < 64; m <<= 1) {
      dot += __shfl_xor(dot, m, 64);
      nn  += __shfl_xor(nn, m, 64);
    }
    if (lane == 0) eS[a] = dot / (unorm * fmaxf(sqrtf(nn), 1e-8f));
  }
  __syncthreads();

  // softmax over 32 (from LDS broadcast reads)
  float w[32];
  float mx = -1e30f;
#pragma unroll
  for (int a = 0; a < 32; ++a) mx = fmaxf(mx, eS[a]);
  float S = 0.f;
#pragma unroll
  for (int a = 0; a < 32; ++a) { w[a] = __expf(eS[a] - mx); S += w[a]; }
  const float inv = 1.0f / S;

  // c combine: thread owns cols g0,g0+1; u32 column reads (2-way, free)
  const int g0 = tid * 2;
  const int p = ((g0 >> 3) & 1) * 512 + (g0 >> 4) * 8 + (g0 & 7);
  float sc0 = 0.f, sc1 = 0.f;
#pragma unroll
  for (int a = 0; a < 32; ++a) {
    const u32 cv = *(const u32*)(cS + a * 1024 + p);
    sc0 += w[a] * __uint_as_float(cv << 16);
    sc1 += w[a] * __uint_as_float(cv & 0xffff0000u);
  }
  float* orow = out + ((size_t)b * CHART_ROWS + 256 + step) * 2048;
  *(float2*)(orow + g0) = make_float2(sc0 * inv, sc1 * inv);
  __syncthreads();            // all cS reads done; buffer reused below

  // h partials: thread sums its 4 a-rows for its 16 cols, stash to LDS
  float* rS = (float*)cS;     // [wave][1024] floats, swizzled for b128 writes
  float ph[16];
#pragma unroll
  for (int jj = 0; jj < 16; ++jj) ph[jj] = 0.f;
#pragma unroll
  for (int t = 0; t < 4; ++t) {
    const float wa = w[t * 8 + wave];
#pragma unroll
    for (int k = 0; k < 8; ++k) {
      const u32 pk2 = hPk[t * 8 + k];
      const int jj0 = (k >> 2) * 8 + (k & 3) * 2;
      ph[jj0]     += wa * __uint_as_float(pk2 << 16);
      ph[jj0 + 1] += wa * __uint_as_float(pk2 & 0xffff0000u);
    }
  }
#pragma unroll
  for (int s = 0; s < 4; ++s) {
    float4 v = make_float4(ph[s * 4], ph[s * 4 + 1], ph[s * 4 + 2], ph[s * 4 + 3]);
    // col g = l*16 + s*4 + k stored at word wave*1024 + s*256 + l*4 + k
    *(float4*)(rS + wave * 1024 + s * 256 + lane * 4) = v;   // lane-contiguous
  }
  __syncthreads();

  // reduce 8 wave-partials for cols g0,g0+1
  const int l_own = g0 >> 4, s_ = (g0 >> 2) & 3, k_ = g0 & 3;
  float sh0 = 0.f, sh1 = 0.f;
#pragma unroll
  for (int w8 = 0; w8 < 8; ++w8) {
    const float2 v = *(const float2*)(rS + w8 * 1024 + s_ * 256 + l_own * 4 + k_);
    sh0 += v.x; sh1 += v.y;
  }
  *(float2*)(orow + 1024 + g0) = make_float2(sh0 * inv, sh1 * inv);
}

extern "C" void kernel_launch(void* const* d_in, const int* in_sizes, int n_in,
                              void* d_out, int out_size, void* d_ws, size_t ws_size,
                              hipStream_t stream) {
  (void)in_sizes; (void)n_in; (void)out_size;
  const float* chart = (const float*)d_in[0];
  const int*   ops   = (const int*)d_in[1];
  // d_in[2] = start_index (256, hard-coded)
  const float* U     = (const float*)d_in[3];
  const float* bias  = (const float*)d_in[4];
  const float* eu    = (const float*)d_in[5];
  float* out = (float*)d_out;
  char* ws = (char*)d_ws;

  u16*      Ubf = (u16*)ws;                       // 20,971,520 B
  u16*      chb = (u16*)(ws + 20971520);          // 16,777,216 B
  u16*      chc = (u16*)(ws + 37748736);          // 16,777,216 B
  _Float16* P   = (_Float16*)(ws + 54525952);     // big: 167,772,160 B (8 slabs)
                                                  // small: 41,943,040 B (2 slabs)
  const size_t SLAB = (size_t)2048 * 5120;        // _Float16 per slab
  const bool big = ws_size >= (size_t)54525952 + 8 * SLAB * 2;

  k_cvt_u<<<10240, 256, 0, stream>>>((const float4*)U, Ubf);
  k_cvt_chart<<<8192, 256, 0, stream>>>(chart, chb, chc, out);

  if (big) {
    // 1280 tiles (20 bx x 2 uh x 4 bg x 8 mt), 256 persistent blocks x 5 tiles
    k_gemm_p<<<256, 512, 0, stream>>>(chb, Ubf, bias, P, 1280, 4, 0);
    for (int bg = 0; bg < 4; ++bg)
      k_fused<<<1024, 512, 0, stream>>>(chc, P + (size_t)(2 * bg) * SLAB, ops, eu, out, bg);
  } else {
    for (int bg = 0; bg < 4; ++bg) {
      // 320 tiles of this bg, 256 blocks (64 blocks chain a 2nd tile)
      k_gemm_p<<<256, 512, 0, stream>>>(chb, Ubf, bias, P, 320, 1, bg);
      k_fused<<<1024, 512, 0, stream>>>(chc, P, ops, eu, out, bg);
    }
  }
}

// Round 4
// 714.541 us; speedup vs baseline: 1.1248x; 1.1248x over previous
//
#include <hip/hip_runtime.h>

// SequentialChart: ops < START(256) => steps independent. Algebraic cut:
// PL[b,op]=U_left@h(b,op), PR[b,op]=U_right@h(b,op) (16x fewer FLOPs),
// preact = PL[opL]+PR[opR] (bias folded into PL at GEMM epilogue).
// log2e folded into U/bias at cvt time: gates use raw v_exp_f32 (exp2).
// GEMM: round-2 non-persistent 256x256 8-phase schedule (T2 swizzle +
// T3/T4 counted vmcnt + T5 setprio), BK=64, 8 waves, 128KB LDS, merged
// over all bg (1280 blocks = 5 exact rounds). Stores AFTER the pipeline.
// k_fused: column-PHASED gathers -- phase sub covers contiguous h-cols
// [sub*512,+512) so the per-XCD P working set is 2.5MB (< 4MB L2),
// cutting the ~5x P re-fetch that made k_fused L2-miss-bound.

typedef unsigned int u32;
typedef unsigned short u16;
typedef __attribute__((ext_vector_type(8))) short short8;
typedef __attribute__((ext_vector_type(4))) float f32x4;
typedef __attribute__((ext_vector_type(4))) u16 u16x4;
typedef __attribute__((ext_vector_type(8))) u16 u16x8;
typedef _Float16 h8 __attribute__((ext_vector_type(8)));

#define CHART_ROWS 384
#define L2E 1.4426950408889634f

__device__ __forceinline__ u16 f2bf(float f) {           // fp32 -> bf16 RNE
  u32 u = __float_as_uint(f);
  u32 r = u + 0x7fffu + ((u >> 16) & 1u);
  return (u16)(r >> 16);
}
__device__ __forceinline__ float bf2f(u16 v) { return __uint_as_float(((u32)v) << 16); }
// preact pre-scaled by -log2e: sigmoid(x) = 1/(1+2^(-x*log2e))
__device__ __forceinline__ float sig2(float p) {
  return __builtin_amdgcn_rcpf(1.0f + __builtin_amdgcn_exp2f(p));
}
// preact pre-scaled by +2*log2e: tanh(x) = 1 - 2/(1+2^(2x*log2e))
__device__ __forceinline__ float tanh2(float p) {
  return 1.0f - 2.0f * __builtin_amdgcn_rcpf(1.0f + __builtin_amdgcn_exp2f(p));
}
// runtime-argument tanh (for tanh(c)); compiler folds 2*log2e into one mul
__device__ __forceinline__ float fast_tanh(float x) {
  return 1.0f - 2.0f * __builtin_amdgcn_rcpf(1.0f + __builtin_amdgcn_exp2f(2.0f * L2E * x));
}

__device__ __forceinline__ void async16(const void* g, void* l) {
  __builtin_amdgcn_global_load_lds((const __attribute__((address_space(1))) u32*)g,
                                   (__attribute__((address_space(3))) u32*)l, 16, 0, 0);
}

#define BAR() __builtin_amdgcn_s_barrier()
#define VMCNT4 asm volatile("s_waitcnt vmcnt(4)" ::: "memory")
#define VMCNT0 asm volatile("s_waitcnt vmcnt(0)" ::: "memory")

// ---- U (5120x2048 fp32) -> bf16, scaled by -log2e (sigmoid rows) / +2log2e (u rows)
__global__ void k_cvt_u(const float4* __restrict__ U4, u16* __restrict__ Ubf) {
  int i = blockIdx.x * blockDim.x + threadIdx.x;   // 2,621,440 threads
  int row = i >> 9;                                // 512 float4 per 2048-col row
  float sc = (row < 4096) ? -L2E : (2.0f * L2E);
  float4 v = U4[i];
  u16x4 o = {f2bf(v.x * sc), f2bf(v.y * sc), f2bf(v.z * sc), f2bf(v.w * sc)};
  *(u16x4*)(Ubf + (size_t)i * 4) = o;
}

// ---- chart rows<256: h-half -> chb, c-half -> chc; also copy rows<256 to out
__global__ void k_cvt_chart(const float* __restrict__ chart,
                            u16* __restrict__ chb, u16* __restrict__ chc,
                            float* __restrict__ out) {
  int i = blockIdx.x * blockDim.x + threadIdx.x;   // 2,097,152 threads
  int row = i >> 8;                 // b*256 + op, < 8192
  int k4 = (i & 255) * 4;
  int b = row >> 8, op = row & 255;
  const size_t base = (size_t)(b * CHART_ROWS + op) * 2048;
  const float4 vh = *(const float4*)(chart + base + 1024 + k4);
  const float4 vc = *(const float4*)(chart + base + k4);
  u16x4 oh = {f2bf(vh.x), f2bf(vh.y), f2bf(vh.z), f2bf(vh.w)};
  u16x4 oc = {f2bf(vc.x), f2bf(vc.y), f2bf(vc.z), f2bf(vc.w)};
  *(u16x4*)(chb + (size_t)row * 1024 + k4) = oh;
  *(u16x4*)(chc + (size_t)row * 1024 + k4) = oc;
  *(float4*)(out + base + k4) = vc;          // rows < 256 pass through
  *(float4*)(out + base + 1024 + k4) = vh;   // rows >= 256 written by k_fused
}

// ---- P[bgh][2048 rows][5120] = chb-rows @ U-half (+bias*scale on half0)
// 256x256 tile, BK=64, 8 waves (2Mx4N), 8-phase double-buffered pipeline.
// grid: x = 20 N-tiles, y = nbgh*8 (bgh | mtile). bgh = bg*2 + uhalf.
#define LOAD_A(BUFO, MH) do { \
  _Pragma("unroll") \
  for (int i_ = 0; i_ < 4; ++i_) { \
    a[0][i_] = *(const short8*)(As + (BUFO) + am + (MH)*4096 + i_*1024 + sl0); \
    a[1][i_] = *(const short8*)(As + (BUFO) + am + (MH)*4096 + i_*1024 + sl1); \
  } } while (0)

#define LOAD_B(BUFO, NH, BR) do { \
  _Pragma("unroll") \
  for (int j_ = 0; j_ < 2; ++j_) { \
    BR[0][j_] = *(const short8*)(Bs + (BUFO) + bm + (NH)*2048 + j_*1024 + sl0); \
    BR[1][j_] = *(const short8*)(Bs + (BUFO) + bm + (NH)*2048 + j_*1024 + sl1); \
  } } while (0)

#define MFMA_Q(MH, NH, BR) do { \
  __builtin_amdgcn_s_setprio(1); \
  _Pragma("unroll") \
  for (int kk_ = 0; kk_ < 2; ++kk_) \
    _Pragma("unroll") \
    for (int i_ = 0; i_ < 4; ++i_) \
      _Pragma("unroll") \
      for (int j_ = 0; j_ < 2; ++j_) \
        acc[(MH)*4+i_][(NH)*2+j_] = __builtin_amdgcn_mfma_f32_16x16x32_bf16( \
            a[kk_][i_], BR[kk_][j_], acc[(MH)*4+i_][(NH)*2+j_], 0, 0, 0); \
  __builtin_amdgcn_s_setprio(0); } while (0)

__global__ __launch_bounds__(512, 2) void k_gemm_p(
    const u16* __restrict__ chb, const u16* __restrict__ Ubf,
    const float* __restrict__ bias, _Float16* __restrict__ P, int bgh_base)
{
  __shared__ u16 As[2 * 256 * 64];   // 64 KB: two K-tile buffers (halves stacked)
  __shared__ u16 Bs[2 * 256 * 64];   // 64 KB

  const int tid = threadIdx.x;
  const int wid = tid >> 6, lane = tid & 63;
  const int lane15 = lane & 15, quad = lane >> 4;
  const int wr = wid >> 2, wc = wid & 3;

  // XCD-aware bijective swizzle (nwg % 8 == 0 in both launch shapes)
  const int nwg = gridDim.x * gridDim.y;
  const int flat = blockIdx.y * gridDim.x + blockIdx.x;
  const int swz = (flat & 7) * (nwg >> 3) + (flat >> 3);
  const int bx = swz % 20;                 // N tile (0..19)
  const int by = swz / 20;
  const int bghl = by >> 3;                // local bgh slab in P
  const int bgh = bgh_base + bghl;
  const int bg = bgh >> 1, uhalf = bgh & 1;
  const int mtile = by & 7;

  // staging: half-tile = 128 rows x 64 cols bf16 = 16KB = 2 rounds x 512 thr x 16B
  // chunk idx = rnd*512+tid: row r=idx>>3 (0..127), slot s=idx&7, src chunk c=s^(r&7)
  const u16* aSrc[2]; const u16* bSrc[2]; int dOff[2];
#pragma unroll
  for (int rnd = 0; rnd < 2; ++rnd) {
    int idx = rnd * 512 + tid;
    int r = idx >> 3, s = idx & 7, c = s ^ (r & 7);
    aSrc[rnd] = chb + (size_t)(bg * 2048 + mtile * 256 + r) * 1024 + c * 8;
    bSrc[rnd] = Ubf + (size_t)(bx * 256 + r) * 2048 + uhalf * 1024 + c * 8;
    dOff[rnd] = idx * 8;                   // u16 units
  }
  auto STAGE_A = [&](int buf, int h, int T) {
#pragma unroll
    for (int rnd = 0; rnd < 2; ++rnd)
      async16(aSrc[rnd] + (size_t)h * 131072 + T * 64,
              As + buf * 16384 + h * 8192 + dOff[rnd]);
  };
  auto STAGE_B = [&](int buf, int h, int T) {
#pragma unroll
    for (int rnd = 0; rnd < 2; ++rnd)
      async16(bSrc[rnd] + (size_t)h * 262144 + T * 64,
              Bs + buf * 16384 + h * 8192 + dOff[rnd]);
  };

  // fragment read bases; m&7 == g&7 == lane15&7 (all tile offsets are mult of 8)
  const int sl0 = ((0 * 4 + quad) ^ (lane15 & 7)) * 8;   // kk=0 slot
  const int sl1 = ((1 * 4 + quad) ^ (lane15 & 7)) * 8;   // kk=1 slot
  const int am = (wr * 128 + lane15) * 64;   // + mh*4096 + i*1024
  const int bm = (wc * 64 + lane15) * 64;    // + nh*2048 + j*1024

  f32x4 acc[8][4];
#pragma unroll
  for (int m_ = 0; m_ < 8; ++m_)
#pragma unroll
    for (int n_ = 0; n_ < 4; ++n_) acc[m_][n_] = (f32x4){0.f, 0.f, 0.f, 0.f};

  short8 a[2][4], b0[2][2], b1[2][2];

  // prologue: tile0 fully + tile1 B-halves; tile1 A staged in iter0 p1/p2
  STAGE_B(0, 0, 0); STAGE_B(0, 1, 0); STAGE_A(0, 0, 0); STAGE_A(0, 1, 0);
  STAGE_B(1, 0, 1); STAGE_B(1, 1, 1);
  VMCNT4;                                  // tile0 landed (tile1-B in flight)
  BAR();

  for (int it = 0; it < 8; ++it) {
    const int T1 = 2 * it + 1, T2 = 2 * it + 2, T3 = 2 * it + 3;
    const bool e2 = (T2 < 16), e3 = (T3 < 16);
    // ---- phases 1-4: tile 2it from buf0 ----
    LOAD_A(0, 0); LOAD_B(0, 0, b0);
    STAGE_A(1, 0, T1);
    BAR(); MFMA_Q(0, 0, b0); BAR();

    LOAD_B(0, 1, b1);
    STAGE_A(1, 1, T1);
    BAR(); MFMA_Q(0, 1, b1); BAR();

    LOAD_A(0, 1);
    if (e2) STAGE_B(0, 0, T2);             // buf0 B free after phase 2
    BAR(); MFMA_Q(1, 0, b0); BAR();

    if (e2) STAGE_B(0, 1, T2);
    BAR(); MFMA_Q(1, 1, b1);
    if (e2) { VMCNT4; } else { VMCNT0; }   // tile 2it+1 fully landed
    BAR();
    // ---- phases 5-8: tile 2it+1 from buf1 ----
    LOAD_A(16384, 0); LOAD_B(16384, 0, b0);
    if (e2) STAGE_A(0, 0, T2);             // buf0 A free after phase 3
    BAR(); MFMA_Q(0, 0, b0); BAR();

    LOAD_B(16384, 1, b1);
    if (e2) STAGE_A(0, 1, T2);
    BAR(); MFMA_Q(0, 1, b1); BAR();

    LOAD_A(16384, 1);
    if (e3) STAGE_B(1, 0, T3);             // buf1 B free after phase 6
    BAR(); MFMA_Q(1, 0, b0); BAR();

    if (e3) STAGE_B(1, 1, T3);
    BAR(); MFMA_Q(1, 1, b1);
    if (e3) { VMCNT4; }                    // tile 2it+2 fully landed
    BAR();
  }

  // epilogue: bias (half0 only, pre-scaled) + fp16 store
  float bb[4];
#pragma unroll
  for (int nt = 0; nt < 4; ++nt) {
    int g = bx * 256 + wc * 64 + nt * 16 + lane15;
    float sc = (g < 4096) ? -L2E : (2.0f * L2E);
    bb[nt] = (uhalf == 0) ? bias[g] * sc : 0.f;
  }
  _Float16* Pb = P + ((size_t)bghl * 2048 + mtile * 256 + wr * 128) * 5120
               + bx * 256 + wc * 64;
#pragma unroll
  for (int mt = 0; mt < 8; ++mt)
#pragma unroll
    for (int rg = 0; rg < 4; ++rg) {
      _Float16* pr = Pb + (size_t)(mt * 16 + quad * 4 + rg) * 5120;
#pragma unroll
      for (int nt = 0; nt < 4; ++nt)
        pr[nt * 16 + lane15] = (_Float16)(acc[mt][nt][rg] + bb[nt]);
    }
}

// ---- fused: gather-add preact + gates + energy + softmax + combine ----
// Column-phased: phase sub gathers contiguous h-cols [sub*512,+512) of all
// gate segments -> per-XCD instantaneous P working set 2.5MB (fits 4MB L2).
// Lane owns cols sub*512 + lane*8 .. +8. cS is linear [a][col] bf16.
// grid = nbg*1024; block (bgl | step | b_local), b_local = XCD-affine.
__global__ __launch_bounds__(512, 4) void k_fused(
    const u16* __restrict__ chc, const _Float16* __restrict__ P,
    const int* __restrict__ ops, const float* __restrict__ eu,
    float* __restrict__ out, int bg0)
{
  __shared__ u16 cS[32 * 1024];   // 64 KB; reused as float[8*1024] for h-reduce
  __shared__ float eS[32];

  const int tid = threadIdx.x;
  const int wave = tid >> 6, lane = tid & 63;
  const int flat = blockIdx.x;
  const int b_local = flat & 7;     // XCD-affine: same-XCD blocks share b
  const int idx = flat >> 3;
  const int step = idx & 127;
  const int bgl = idx >> 7;         // slab index within P
  const int bg = bg0 + bgl;
  const int b = bg * 8 + b_local;
  const size_t HSLAB = (size_t)2048 * 5120;
  const _Float16* Pl = P + (size_t)(2 * bgl) * HSLAB;

  // energy_u for this lane's 16 cols: u[sub][j] = eu[sub*512 + lane*8 + j]
  float uu[2][8];
#pragma unroll
  for (int sub = 0; sub < 2; ++sub) {
    *(float4*)&uu[sub][0] = *(const float4*)(eu + sub * 512 + lane * 8);
    *(float4*)&uu[sub][4] = *(const float4*)(eu + sub * 512 + lane * 8 + 4);
  }
  float part = 0.f;
#pragma unroll
  for (int sub = 0; sub < 2; ++sub)
#pragma unroll
    for (int j = 0; j < 8; ++j) part += uu[sub][j] * uu[sub][j];
#pragma unroll
  for (int m = 1; m < 64; m <<= 1) part += __shfl_xor(part, m, 64);
  const float unorm = fmaxf(sqrtf(part), 1e-8f);

  int opLr[4], opRr[4];
#pragma unroll
  for (int t = 0; t < 4; ++t) {
    const int a = t * 8 + wave;
    const long opflat = (((long)step * 32 + b) * 32 + a) * 2;
    opLr[t] = ops[opflat]; opRr[t] = ops[opflat + 1];
  }

  u32 hPk[32];    // packed bf16 h: hPk[sub*16 + t*4 + (j>>1)] = cols (cb+2k, cb+2k+1)
  float dotA[4] = {0.f, 0.f, 0.f, 0.f}, nnA[4] = {0.f, 0.f, 0.f, 0.f};

#pragma unroll
  for (int sub = 0; sub < 2; ++sub) {
    const int cb = sub * 512 + lane * 8;   // contiguous col base for this phase
#pragma unroll
    for (int t = 0; t < 4; ++t) {
      const int a = t * 8 + wave;
      const _Float16* PLp = Pl + (size_t)(b_local * 256 + opLr[t]) * 5120 + cb;
      const _Float16* PRp = Pl + HSLAB + (size_t)(b_local * 256 + opRr[t]) * 5120 + cb;
      const u16* ccL = chc + (size_t)(b * 256 + opLr[t]) * 1024 + cb;
      const u16* ccR = chc + (size_t)(b * 256 + opRr[t]) * 1024 + cb;
      h8 pre[5];
#pragma unroll
      for (int q = 0; q < 5; ++q)
        pre[q] = *(const h8*)(PLp + q * 1024) + *(const h8*)(PRp + q * 1024);
      const u16x8 cl = *(const u16x8*)ccL;
      const u16x8 cr = *(const u16x8*)ccR;
      u16x8 co;
      u32 lo = 0;
#pragma unroll
      for (int j = 0; j < 8; ++j) {
        float pi  = (float)pre[0][j];   // pre-scaled by -log2e
        float pfL = (float)pre[1][j];
        float pfR = (float)pre[2][j];
        float po  = (float)pre[3][j];
        float pu  = (float)pre[4][j];   // pre-scaled by +2*log2e
        float cv = sig2(pfL) * bf2f(cl[j]) + sig2(pfR) * bf2f(cr[j])
                 + sig2(pi) * tanh2(pu);
        float hv = sig2(po) * fast_tanh(cv);
        co[j] = f2bf(cv);
        if ((j & 1) == 0) lo = (u32)f2bf(hv);
        else hPk[sub * 16 + t * 4 + (j >> 1)] = lo | ((u32)f2bf(hv) << 16);
        dotA[t] += hv * uu[sub][j];
        nnA[t]  += hv * hv;
      }
      *(u16x8*)(cS + a * 1024 + cb) = co;   // linear [a][col], b128, lane-contig
    }
  }
#pragma unroll
  for (int t = 0; t < 4; ++t) {
    float d = dotA[t], n = nnA[t];
#pragma unroll
    for (int m = 1; m < 64; m <<= 1) {
      d += __shfl_xor(d, m, 64);
      n += __shfl_xor(n, m, 64);
    }
    if (lane == 0) eS[t * 8 + wave] = d / (unorm * fmaxf(sqrtf(n), 1e-8f));
  }
  __syncthreads();

  // softmax over 32 (from LDS broadcast reads)
  float w[32];
  float mx = -1e30f;
#pragma unroll
  for (int a = 0; a < 32; ++a) mx = fmaxf(mx, eS[a]);
  float S = 0.f;
#pragma unroll
  for (int a = 0; a < 32; ++a) { w[a] = __expf(eS[a] - mx); S += w[a]; }
  const float inv = 1.0f / S;

  // c combine: thread owns cols g0,g0+1; u32 reads, lane-consecutive banks
  const int g0 = tid * 2;
  float sc0 = 0.f, sc1 = 0.f;
#pragma unroll
  for (int a = 0; a < 32; ++a) {
    const u32 cv = *(const u32*)(cS + a * 1024 + g0);
    sc0 += w[a] * __uint_as_float(cv << 16);
    sc1 += w[a] * __uint_as_float(cv & 0xffff0000u);
  }
  float* orow = out + ((size_t)b * CHART_ROWS + 256 + step) * 2048;
  *(float2*)(orow + g0) = make_float2(sc0 * inv, sc1 * inv);
  __syncthreads();            // all cS reads done; buffer reused below

  // h partials: thread sums its 4 a-rows for its 16 cols, stash to LDS.
  // word layout: wave*1024 + sub*512 + jj*64 + lane  (lane-contiguous writes)
  float* rS = (float*)cS;
  float ph[2][8];
#pragma unroll
  for (int sub = 0; sub < 2; ++sub)
#pragma unroll
    for (int jj = 0; jj < 8; ++jj) ph[sub][jj] = 0.f;
#pragma unroll
  for (int t = 0; t < 4; ++t) {
    const float wa = w[t * 8 + wave];
#pragma unroll
    for (int sub = 0; sub < 2; ++sub)
#pragma unroll
      for (int k = 0; k < 4; ++k) {
        const u32 pk2 = hPk[sub * 16 + t * 4 + k];
        ph[sub][2 * k]     += wa * __uint_as_float(pk2 << 16);
        ph[sub][2 * k + 1] += wa * __uint_as_float(pk2 & 0xffff0000u);
      }
  }
#pragma unroll
  for (int sub = 0; sub < 2; ++sub)
#pragma unroll
    for (int jj = 0; jj < 8; ++jj)
      rS[wave * 1024 + sub * 512 + jj * 64 + lane] = ph[sub][jj];
  __syncthreads();

  // reduce 8 wave-partials for cols g0, g0+1
  const int sub0 = g0 >> 9, r0 = g0 & 511, l0 = r0 >> 3, j0 = r0 & 7;
  const int w0 = sub0 * 512 + j0 * 64 + l0;     // col g0+1 at w0 + 64 (j0 even)
  float sh0 = 0.f, sh1 = 0.f;
#pragma unroll
  for (int w8 = 0; w8 < 8; ++w8) {
    sh0 += rS[w8 * 1024 + w0];
    sh1 += rS[w8 * 1024 + w0 + 64];
  }
  *(float2*)(orow + 1024 + g0) = make_float2(sh0 * inv, sh1 * inv);
}

extern "C" void kernel_launch(void* const* d_in, const int* in_sizes, int n_in,
                              void* d_out, int out_size, void* d_ws, size_t ws_size,
                              hipStream_t stream) {
  (void)in_sizes; (void)n_in; (void)out_size;
  const float* chart = (const float*)d_in[0];
  const int*   ops   = (const int*)d_in[1];
  // d_in[2] = start_index (256, hard-coded)
  const float* U     = (const float*)d_in[3];
  const float* bias  = (const float*)d_in[4];
  const float* eu    = (const float*)d_in[5];
  float* out = (float*)d_out;
  char* ws = (char*)d_ws;

  u16*      Ubf = (u16*)ws;                       // 20,971,520 B
  u16*      chb = (u16*)(ws + 20971520);          // 16,777,216 B
  u16*      chc = (u16*)(ws + 37748736);          // 16,777,216 B
  _Float16* P   = (_Float16*)(ws + 54525952);     // big: 167,772,160 B (8 slabs)
                                                  // small: 41,943,040 B (2 slabs)
  const size_t SLAB = (size_t)2048 * 5120;        // _Float16 per slab
  const bool big = ws_size >= (size_t)54525952 + 8 * SLAB * 2;

  k_cvt_u<<<10240, 256, 0, stream>>>((const float4*)U, Ubf);
  k_cvt_chart<<<8192, 256, 0, stream>>>(chart, chb, chc, out);

  if (big) {
    // 1280 tiles (20 bx x 8 bgh x 8 mt), 5 exact rounds of 256 blocks
    k_gemm_p<<<dim3(20, 64), 512, 0, stream>>>(chb, Ubf, bias, P, 0);
    // single fused dispatch over all bg (4096 blocks)
    k_fused<<<4096, 512, 0, stream>>>(chc, P, ops, eu, out, 0);
  } else {
    for (int bg = 0; bg < 4; ++bg) {
      k_gemm_p<<<dim3(20, 16), 512, 0, stream>>>(chb, Ubf, bias, P, 2 * bg);
      k_fused<<<1024, 512, 0, stream>>>(chc, P, ops, eu, out, bg);
    }
  }
}

// Round 5
// 685.266 us; speedup vs baseline: 1.1728x; 1.0427x over previous
//
#include <hip/hip_runtime.h>

// SequentialChart: ops < START(256) => steps independent. Algebraic cut:
// PL[b,op]=U_left@h(b,op), PR[b,op]=U_right@h(b,op) (16x fewer FLOPs),
// preact = PL[opL]+PR[opR] (bias folded into PL at GEMM epilogue).
// log2e folded into U/bias at cvt time: gates use raw v_exp_f32 (exp2).
// GEMM: 256x256 8-phase schedule (T2 swizzle + T3/T4 counted vmcnt + T5
// setprio), BK=64, 8 waves, 128KB LDS, merged over all bg (1280 blocks).
// k_fused: column-phased gathers (per-XCD P working set fits L2) and --
// critically -- NO REGISTER SPILL: launch_bounds(512,2) gives 128 VGPRs
// (LDS already caps occupancy at 2 blocks/CU; the old (512,4) bound forced
// a 64-VGPR cap and ~600MB of scratch traffic per dispatch). Softmax
// weights live in LDS (wS) instead of a 32-reg array.

typedef unsigned int u32;
typedef unsigned short u16;
typedef __attribute__((ext_vector_type(8))) short short8;
typedef __attribute__((ext_vector_type(4))) float f32x4;
typedef __attribute__((ext_vector_type(4))) u16 u16x4;
typedef __attribute__((ext_vector_type(8))) u16 u16x8;
typedef _Float16 h8 __attribute__((ext_vector_type(8)));

#define CHART_ROWS 384
#define L2E 1.4426950408889634f

__device__ __forceinline__ u16 f2bf(float f) {           // fp32 -> bf16 RNE
  u32 u = __float_as_uint(f);
  u32 r = u + 0x7fffu + ((u >> 16) & 1u);
  return (u16)(r >> 16);
}
__device__ __forceinline__ float bf2f(u16 v) { return __uint_as_float(((u32)v) << 16); }
// preact pre-scaled by -log2e: sigmoid(x) = 1/(1+2^(-x*log2e))
__device__ __forceinline__ float sig2(float p) {
  return __builtin_amdgcn_rcpf(1.0f + __builtin_amdgcn_exp2f(p));
}
// preact pre-scaled by +2*log2e: tanh(x) = 1 - 2/(1+2^(2x*log2e))
__device__ __forceinline__ float tanh2(float p) {
  return 1.0f - 2.0f * __builtin_amdgcn_rcpf(1.0f + __builtin_amdgcn_exp2f(p));
}
// runtime-argument tanh (for tanh(c)); compiler folds 2*log2e into one mul
__device__ __forceinline__ float fast_tanh(float x) {
  return 1.0f - 2.0f * __builtin_amdgcn_rcpf(1.0f + __builtin_amdgcn_exp2f(2.0f * L2E * x));
}

__device__ __forceinline__ void async16(const void* g, void* l) {
  __builtin_amdgcn_global_load_lds((const __attribute__((address_space(1))) u32*)g,
                                   (__attribute__((address_space(3))) u32*)l, 16, 0, 0);
}

#define BAR() __builtin_amdgcn_s_barrier()
#define VMCNT4 asm volatile("s_waitcnt vmcnt(4)" ::: "memory")
#define VMCNT0 asm volatile("s_waitcnt vmcnt(0)" ::: "memory")

// ---- U (5120x2048 fp32) -> bf16, scaled by -log2e (sigmoid rows) / +2log2e (u rows)
__global__ void k_cvt_u(const float4* __restrict__ U4, u16* __restrict__ Ubf) {
  int i = blockIdx.x * blockDim.x + threadIdx.x;   // 2,621,440 threads
  int row = i >> 9;                                // 512 float4 per 2048-col row
  float sc = (row < 4096) ? -L2E : (2.0f * L2E);
  float4 v = U4[i];
  u16x4 o = {f2bf(v.x * sc), f2bf(v.y * sc), f2bf(v.z * sc), f2bf(v.w * sc)};
  *(u16x4*)(Ubf + (size_t)i * 4) = o;
}

// ---- chart rows<256: h-half -> chb, c-half -> chc; also copy rows<256 to out
__global__ void k_cvt_chart(const float* __restrict__ chart,
                            u16* __restrict__ chb, u16* __restrict__ chc,
                            float* __restrict__ out) {
  int i = blockIdx.x * blockDim.x + threadIdx.x;   // 2,097,152 threads
  int row = i >> 8;                 // b*256 + op, < 8192
  int k4 = (i & 255) * 4;
  int b = row >> 8, op = row & 255;
  const size_t base = (size_t)(b * CHART_ROWS + op) * 2048;
  const float4 vh = *(const float4*)(chart + base + 1024 + k4);
  const float4 vc = *(const float4*)(chart + base + k4);
  u16x4 oh = {f2bf(vh.x), f2bf(vh.y), f2bf(vh.z), f2bf(vh.w)};
  u16x4 oc = {f2bf(vc.x), f2bf(vc.y), f2bf(vc.z), f2bf(vc.w)};
  *(u16x4*)(chb + (size_t)row * 1024 + k4) = oh;
  *(u16x4*)(chc + (size_t)row * 1024 + k4) = oc;
  *(float4*)(out + base + k4) = vc;          // rows < 256 pass through
  *(float4*)(out + base + 1024 + k4) = vh;   // rows >= 256 written by k_fused
}

// ---- P[bgh][2048 rows][5120] = chb-rows @ U-half (+bias*scale on half0)
// 256x256 tile, BK=64, 8 waves (2Mx4N), 8-phase double-buffered pipeline.
// grid: x = 20 N-tiles, y = nbgh*8 (bgh | mtile). bgh = bg*2 + uhalf.
#define LOAD_A(BUFO, MH) do { \
  _Pragma("unroll") \
  for (int i_ = 0; i_ < 4; ++i_) { \
    a[0][i_] = *(const short8*)(As + (BUFO) + am + (MH)*4096 + i_*1024 + sl0); \
    a[1][i_] = *(const short8*)(As + (BUFO) + am + (MH)*4096 + i_*1024 + sl1); \
  } } while (0)

#define LOAD_B(BUFO, NH, BR) do { \
  _Pragma("unroll") \
  for (int j_ = 0; j_ < 2; ++j_) { \
    BR[0][j_] = *(const short8*)(Bs + (BUFO) + bm + (NH)*2048 + j_*1024 + sl0); \
    BR[1][j_] = *(const short8*)(Bs + (BUFO) + bm + (NH)*2048 + j_*1024 + sl1); \
  } } while (0)

#define MFMA_Q(MH, NH, BR) do { \
  __builtin_amdgcn_s_setprio(1); \
  _Pragma("unroll") \
  for (int kk_ = 0; kk_ < 2; ++kk_) \
    _Pragma("unroll") \
    for (int i_ = 0; i_ < 4; ++i_) \
      _Pragma("unroll") \
      for (int j_ = 0; j_ < 2; ++j_) \
        acc[(MH)*4+i_][(NH)*2+j_] = __builtin_amdgcn_mfma_f32_16x16x32_bf16( \
            a[kk_][i_], BR[kk_][j_], acc[(MH)*4+i_][(NH)*2+j_], 0, 0, 0); \
  __builtin_amdgcn_s_setprio(0); } while (0)

__global__ __launch_bounds__(512, 2) void k_gemm_p(
    const u16* __restrict__ chb, const u16* __restrict__ Ubf,
    const float* __restrict__ bias, _Float16* __restrict__ P, int bgh_base)
{
  __shared__ u16 As[2 * 256 * 64];   // 64 KB: two K-tile buffers (halves stacked)
  __shared__ u16 Bs[2 * 256 * 64];   // 64 KB

  const int tid = threadIdx.x;
  const int wid = tid >> 6, lane = tid & 63;
  const int lane15 = lane & 15, quad = lane >> 4;
  const int wr = wid >> 2, wc = wid & 3;

  // XCD-aware bijective swizzle (nwg % 8 == 0 in both launch shapes)
  const int nwg = gridDim.x * gridDim.y;
  const int flat = blockIdx.y * gridDim.x + blockIdx.x;
  const int swz = (flat & 7) * (nwg >> 3) + (flat >> 3);
  const int bx = swz % 20;                 // N tile (0..19)
  const int by = swz / 20;
  const int bghl = by >> 3;                // local bgh slab in P
  const int bgh = bgh_base + bghl;
  const int bg = bgh >> 1, uhalf = bgh & 1;
  const int mtile = by & 7;

  // staging: half-tile = 128 rows x 64 cols bf16 = 16KB = 2 rounds x 512 thr x 16B
  // chunk idx = rnd*512+tid: row r=idx>>3 (0..127), slot s=idx&7, src chunk c=s^(r&7)
  const u16* aSrc[2]; const u16* bSrc[2]; int dOff[2];
#pragma unroll
  for (int rnd = 0; rnd < 2; ++rnd) {
    int idx = rnd * 512 + tid;
    int r = idx >> 3, s = idx & 7, c = s ^ (r & 7);
    aSrc[rnd] = chb + (size_t)(bg * 2048 + mtile * 256 + r) * 1024 + c * 8;
    bSrc[rnd] = Ubf + (size_t)(bx * 256 + r) * 2048 + uhalf * 1024 + c * 8;
    dOff[rnd] = idx * 8;                   // u16 units
  }
  auto STAGE_A = [&](int buf, int h, int T) {
#pragma unroll
    for (int rnd = 0; rnd < 2; ++rnd)
      async16(aSrc[rnd] + (size_t)h * 131072 + T * 64,
              As + buf * 16384 + h * 8192 + dOff[rnd]);
  };
  auto STAGE_B = [&](int buf, int h, int T) {
#pragma unroll
    for (int rnd = 0; rnd < 2; ++rnd)
      async16(bSrc[rnd] + (size_t)h * 262144 + T * 64,
              Bs + buf * 16384 + h * 8192 + dOff[rnd]);
  };

  // fragment read bases; m&7 == g&7 == lane15&7 (all tile offsets are mult of 8)
  const int sl0 = ((0 * 4 + quad) ^ (lane15 & 7)) * 8;   // kk=0 slot
  const int sl1 = ((1 * 4 + quad) ^ (lane15 & 7)) * 8;   // kk=1 slot
  const int am = (wr * 128 + lane15) * 64;   // + mh*4096 + i*1024
  const int bm = (wc * 64 + lane15) * 64;    // + nh*2048 + j*1024

  f32x4 acc[8][4];
#pragma unroll
  for (int m_ = 0; m_ < 8; ++m_)
#pragma unroll
    for (int n_ = 0; n_ < 4; ++n_) acc[m_][n_] = (f32x4){0.f, 0.f, 0.f, 0.f};

  short8 a[2][4], b0[2][2], b1[2][2];

  // prologue: tile0 fully + tile1 B-halves; tile1 A staged in iter0 p1/p2
  STAGE_B(0, 0, 0); STAGE_B(0, 1, 0); STAGE_A(0, 0, 0); STAGE_A(0, 1, 0);
  STAGE_B(1, 0, 1); STAGE_B(1, 1, 1);
  VMCNT4;                                  // tile0 landed (tile1-B in flight)
  BAR();

  for (int it = 0; it < 8; ++it) {
    const int T1 = 2 * it + 1, T2 = 2 * it + 2, T3 = 2 * it + 3;
    const bool e2 = (T2 < 16), e3 = (T3 < 16);
    // ---- phases 1-4: tile 2it from buf0 ----
    LOAD_A(0, 0); LOAD_B(0, 0, b0);
    STAGE_A(1, 0, T1);
    BAR(); MFMA_Q(0, 0, b0); BAR();

    LOAD_B(0, 1, b1);
    STAGE_A(1, 1, T1);
    BAR(); MFMA_Q(0, 1, b1); BAR();

    LOAD_A(0, 1);
    if (e2) STAGE_B(0, 0, T2);             // buf0 B free after phase 2
    BAR(); MFMA_Q(1, 0, b0); BAR();

    if (e2) STAGE_B(0, 1, T2);
    BAR(); MFMA_Q(1, 1, b1);
    if (e2) { VMCNT4; } else { VMCNT0; }   // tile 2it+1 fully landed
    BAR();
    // ---- phases 5-8: tile 2it+1 from buf1 ----
    LOAD_A(16384, 0); LOAD_B(16384, 0, b0);
    if (e2) STAGE_A(0, 0, T2);             // buf0 A free after phase 3
    BAR(); MFMA_Q(0, 0, b0); BAR();

    LOAD_B(16384, 1, b1);
    if (e2) STAGE_A(0, 1, T2);
    BAR(); MFMA_Q(0, 1, b1); BAR();

    LOAD_A(16384, 1);
    if (e3) STAGE_B(1, 0, T3);             // buf1 B free after phase 6
    BAR(); MFMA_Q(1, 0, b0); BAR();

    if (e3) STAGE_B(1, 1, T3);
    BAR(); MFMA_Q(1, 1, b1);
    if (e3) { VMCNT4; }                    // tile 2it+2 fully landed
    BAR();
  }

  // epilogue: bias (half0 only, pre-scaled) + fp16 store
  float bb[4];
#pragma unroll
  for (int nt = 0; nt < 4; ++nt) {
    int g = bx * 256 + wc * 64 + nt * 16 + lane15;
    float sc = (g < 4096) ? -L2E : (2.0f * L2E);
    bb[nt] = (uhalf == 0) ? bias[g] * sc : 0.f;
  }
  _Float16* Pb = P + ((size_t)bghl * 2048 + mtile * 256 + wr * 128) * 5120
               + bx * 256 + wc * 64;
#pragma unroll
  for (int mt = 0; mt < 8; ++mt)
#pragma unroll
    for (int rg = 0; rg < 4; ++rg) {
      _Float16* pr = Pb + (size_t)(mt * 16 + quad * 4 + rg) * 5120;
#pragma unroll
      for (int nt = 0; nt < 4; ++nt)
        pr[nt * 16 + lane15] = (_Float16)(acc[mt][nt][rg] + bb[nt]);
    }
}

// ---- fused: gather-add preact + gates + energy + softmax + combine ----
// Column-phased: phase sub gathers contiguous h-cols [sub*512,+512).
// launch_bounds(512,2): 128 VGPRs (LDS caps occupancy at 2 blocks/CU
// anyway) -> no scratch spill. Softmax weights in LDS wS, not registers.
__global__ __launch_bounds__(512, 2) void k_fused(
    const u16* __restrict__ chc, const _Float16* __restrict__ P,
    const int* __restrict__ ops, const float* __restrict__ eu,
    float* __restrict__ out, int bg0)
{
  __shared__ u16 cS[32 * 1024];   // 64 KB; reused as float[8*1024] for h-reduce
  __shared__ float eS[32];
  __shared__ float wS[32];

  const int tid = threadIdx.x;
  const int wave = tid >> 6, lane = tid & 63;
  const int flat = blockIdx.x;
  const int b_local = flat & 7;     // XCD-affine: same-XCD blocks share b
  const int idx = flat >> 3;
  const int step = idx & 127;
  const int bgl = idx >> 7;         // slab index within P
  const int bg = bg0 + bgl;
  const int b = bg * 8 + b_local;
  const size_t HSLAB = (size_t)2048 * 5120;
  const _Float16* Pl = P + (size_t)(2 * bgl) * HSLAB;

  // energy_u for this lane's 16 cols: u[sub][j] = eu[sub*512 + lane*8 + j]
  float uu[2][8];
#pragma unroll
  for (int sub = 0; sub < 2; ++sub) {
    *(float4*)&uu[sub][0] = *(const float4*)(eu + sub * 512 + lane * 8);
    *(float4*)&uu[sub][4] = *(const float4*)(eu + sub * 512 + lane * 8 + 4);
  }
  float part = 0.f;
#pragma unroll
  for (int sub = 0; sub < 2; ++sub)
#pragma unroll
    for (int j = 0; j < 8; ++j) part += uu[sub][j] * uu[sub][j];
#pragma unroll
  for (int m = 1; m < 64; m <<= 1) part += __shfl_xor(part, m, 64);
  const float unorm = fmaxf(sqrtf(part), 1e-8f);

  int opLr[4], opRr[4];
#pragma unroll
  for (int t = 0; t < 4; ++t) {
    const int a = t * 8 + wave;
    const long opflat = (((long)step * 32 + b) * 32 + a) * 2;
    opLr[t] = ops[opflat]; opRr[t] = ops[opflat + 1];
  }

  u32 hPk[32];    // packed bf16 h: hPk[sub*16 + t*4 + (j>>1)] = cols (cb+2k, cb+2k+1)
  float dotA[4] = {0.f, 0.f, 0.f, 0.f}, nnA[4] = {0.f, 0.f, 0.f, 0.f};

#pragma unroll
  for (int sub = 0; sub < 2; ++sub) {
    const int cb = sub * 512 + lane * 8;   // contiguous col base for this phase
#pragma unroll
    for (int t = 0; t < 4; ++t) {
      const int a = t * 8 + wave;
      const _Float16* PLp = Pl + (size_t)(b_local * 256 + opLr[t]) * 5120 + cb;
      const _Float16* PRp = Pl + HSLAB + (size_t)(b_local * 256 + opRr[t]) * 5120 + cb;
      const u16* ccL = chc + (size_t)(b * 256 + opLr[t]) * 1024 + cb;
      const u16* ccR = chc + (size_t)(b * 256 + opRr[t]) * 1024 + cb;
      h8 pre[5];
#pragma unroll
      for (int q = 0; q < 5; ++q)
        pre[q] = *(const h8*)(PLp + q * 1024) + *(const h8*)(PRp + q * 1024);
      const u16x8 cl = *(const u16x8*)ccL;
      const u16x8 cr = *(const u16x8*)ccR;
      u16x8 co;
      u32 lo = 0;
#pragma unroll
      for (int j = 0; j < 8; ++j) {
        float pi  = (float)pre[0][j];   // pre-scaled by -log2e
        float pfL = (float)pre[1][j];
        float pfR = (float)pre[2][j];
        float po  = (float)pre[3][j];
        float pu  = (float)pre[4][j];   // pre-scaled by +2*log2e
        float cv = sig2(pfL) * bf2f(cl[j]) + sig2(pfR) * bf2f(cr[j])
                 + sig2(pi) * tanh2(pu);
        float hv = sig2(po) * fast_tanh(cv);
        co[j] = f2bf(cv);
        if ((j & 1) == 0) lo = (u32)f2bf(hv);
        else hPk[sub * 16 + t * 4 + (j >> 1)] = lo | ((u32)f2bf(hv) << 16);
        dotA[t] += hv * uu[sub][j];
        nnA[t]  += hv * hv;
      }
      *(u16x8*)(cS + a * 1024 + cb) = co;   // linear [a][col], b128, lane-contig
    }
  }
#pragma unroll
  for (int t = 0; t < 4; ++t) {
    float d = dotA[t], n = nnA[t];
#pragma unroll
    for (int m = 1; m < 64; m <<= 1) {
      d += __shfl_xor(d, m, 64);
      n += __shfl_xor(n, m, 64);
    }
    if (lane == 0) eS[t * 8 + wave] = d / (unorm * fmaxf(sqrtf(n), 1e-8f));
  }
  __syncthreads();

  // softmax over 32: weights into LDS (broadcast reads), not registers
  float mx = -1e30f;
#pragma unroll
  for (int a = 0; a < 32; ++a) mx = fmaxf(mx, eS[a]);
  if (tid < 32) wS[tid] = __expf(eS[tid] - mx);
  __syncthreads();
  float S = 0.f;
#pragma unroll
  for (int a = 0; a < 32; ++a) S += wS[a];
  const float inv = 1.0f / S;

  // c combine: thread owns cols g0,g0+1; u32 reads, lane-consecutive banks
  const int g0 = tid * 2;
  float sc0 = 0.f, sc1 = 0.f;
#pragma unroll
  for (int a = 0; a < 32; ++a) {
    const float wa = wS[a];
    const u32 cv = *(const u32*)(cS + a * 1024 + g0);
    sc0 += wa * __uint_as_float(cv << 16);
    sc1 += wa * __uint_as_float(cv & 0xffff0000u);
  }
  float* orow = out + ((size_t)b * CHART_ROWS + 256 + step) * 2048;
  *(float2*)(orow + g0) = make_float2(sc0 * inv, sc1 * inv);
  __syncthreads();            // all cS reads done; buffer reused below

  // h partials: thread sums its 4 a-rows for its 16 cols, stash to LDS.
  // word layout: wave*1024 + sub*512 + jj*64 + lane  (lane-contiguous writes)
  float* rS = (float*)cS;
  float ph[2][8];
#pragma unroll
  for (int sub = 0; sub < 2; ++sub)
#pragma unroll
    for (int jj = 0; jj < 8; ++jj) ph[sub][jj] = 0.f;
#pragma unroll
  for (int t = 0; t < 4; ++t) {
    const float wa = wS[t * 8 + wave];
#pragma unroll
    for (int sub = 0; sub < 2; ++sub)
#pragma unroll
      for (int k = 0; k < 4; ++k) {
        const u32 pk2 = hPk[sub * 16 + t * 4 + k];
        ph[sub][2 * k]     += wa * __uint_as_float(pk2 << 16);
        ph[sub][2 * k + 1] += wa * __uint_as_float(pk2 & 0xffff0000u);
      }
  }
#pragma unroll
  for (int sub = 0; sub < 2; ++sub)
#pragma unroll
    for (int jj = 0; jj < 8; ++jj)
      rS[wave * 1024 + sub * 512 + jj * 64 + lane] = ph[sub][jj];
  __syncthreads();

  // reduce 8 wave-partials for cols g0, g0+1
  const int sub0 = g0 >> 9, r0 = g0 & 511, l0 = r0 >> 3, j0 = r0 & 7;
  const int w0 = sub0 * 512 + j0 * 64 + l0;     // col g0+1 at w0 + 64 (j0 even)
  float sh0 = 0.f, sh1 = 0.f;
#pragma unroll
  for (int w8 = 0; w8 < 8; ++w8) {
    sh0 += rS[w8 * 1024 + w0];
    sh1 += rS[w8 * 1024 + w0 + 64];
  }
  *(float2*)(orow + 1024 + g0) = make_float2(sh0 * inv, sh1 * inv);
}

extern "C" void kernel_launch(void* const* d_in, const int* in_sizes, int n_in,
                              void* d_out, int out_size, void* d_ws, size_t ws_size,
                              hipStream_t stream) {
  (void)in_sizes; (void)n_in; (void)out_size;
  const float* chart = (const float*)d_in[0];
  const int*   ops   = (const int*)d_in[1];
  // d_in[2] = start_index (256, hard-coded)
  const float* U     = (const float*)d_in[3];
  const float* bias  = (const float*)d_in[4];
  const float* eu    = (const float*)d_in[5];
  float* out = (float*)d_out;
  char* ws = (char*)d_ws;

  u16*      Ubf = (u16*)ws;                       // 20,971,520 B
  u16*      chb = (u16*)(ws + 20971520);          // 16,777,216 B
  u16*      chc = (u16*)(ws + 37748736);          // 16,777,216 B
  _Float16* P   = (_Float16*)(ws + 54525952);     // big: 167,772,160 B (8 slabs)
                                                  // small: 41,943,040 B (2 slabs)
  const size_t SLAB = (size_t)2048 * 5120;        // _Float16 per slab
  const bool big = ws_size >= (size_t)54525952 + 8 * SLAB * 2;

  k_cvt_u<<<10240, 256, 0, stream>>>((const float4*)U, Ubf);
  k_cvt_chart<<<8192, 256, 0, stream>>>(chart, chb, chc, out);

  if (big) {
    // 1280 tiles (20 bx x 8 bgh x 8 mt), 5 exact rounds of 256 blocks
    k_gemm_p<<<dim3(20, 64), 512, 0, stream>>>(chb, Ubf, bias, P, 0);
    // single fused dispatch over all bg (4096 blocks)
    k_fused<<<4096, 512, 0, stream>>>(chc, P, ops, eu, out, 0);
  } else {
    for (int bg = 0; bg < 4; ++bg) {
      k_gemm_p<<<dim3(20, 16), 512, 0, stream>>>(chb, Ubf, bias, P, 2 * bg);
      k_fused<<<1024, 512, 0, stream>>>(chc, P, ops, eu, out, bg);
    }
  }
}

// Round 7
// 592.219 us; speedup vs baseline: 1.3571x; 1.1571x over previous
//
#include <hip/hip_runtime.h>
#include <hip/hip_fp16.h>

// SequentialChart: ops < START(256) => steps independent. Algebraic cut:
// PL[b,op]=U_left@h(b,op), PR[b,op]=U_right@h(b,op) (16x fewer FLOPs),
// preact = PL[opL]+PR[opR] (bias folded into PL at GEMM epilogue).
// log2e folded into U/bias at cvt time: gates use raw v_exp (exp2).
// GEMM: 256x256 8-phase schedule (T2 swizzle + T3/T4 counted vmcnt + T5
// setprio), BK=64, 8 waves, 128KB LDS, merged over all bg (1280 blocks).
// k_fused v3: ONLINE softmax (e=cos-sim in [-1,1] -> exp(e) safe without
// max-sub) -> no c/h storage at all; Sc/Sh accumulate in f32 regs.
// Packed-f16 gate pipeline (v_pk_* + h2exp2/h2rcp + v_dot2_f32_f16).
// 256-thr blocks, barrier-free main loop, 32KB LDS merge buffer.

typedef unsigned int u32;
typedef unsigned short u16;
typedef __attribute__((ext_vector_type(8))) short short8;
typedef __attribute__((ext_vector_type(4))) float f32x4;
typedef __attribute__((ext_vector_type(4))) u16 u16x4;
typedef _Float16 h8 __attribute__((ext_vector_type(8)));
typedef _Float16 h2v __attribute__((ext_vector_type(2)));
typedef _Float16 h4v __attribute__((ext_vector_type(4)));

#define CHART_ROWS 384
#define L2E 1.4426950408889634f

__device__ __forceinline__ u16 f2bf(float f) {           // fp32 -> bf16 RNE
  u32 u = __float_as_uint(f);
  u32 r = u + 0x7fffu + ((u >> 16) & 1u);
  return (u16)(r >> 16);
}

// packed f16 exp2 / rcp via HIP half2 intrinsics (lower to v_exp_f16/v_rcp_f16)
__device__ __forceinline__ h2v pk_exp2(h2v x) {
  __half2 t = *(__half2*)&x;
  t = h2exp2(t);
  return *(h2v*)&t;
}
__device__ __forceinline__ h2v pk_rcp(h2v x) {
  __half2 t = *(__half2*)&x;
  t = h2rcp(t);
  return *(h2v*)&t;
}

#if __has_builtin(__builtin_amdgcn_fdot2)
__device__ __forceinline__ float fdot2a(h2v a, h2v b, float c) {
  return __builtin_amdgcn_fdot2(a, b, c, false);
}
#else
__device__ __forceinline__ float fdot2a(h2v a, h2v b, float c) {
  return c + (float)a[0] * (float)b[0] + (float)a[1] * (float)b[1];
}
#endif

__device__ __forceinline__ void async16(const void* g, void* l) {
  __builtin_amdgcn_global_load_lds((const __attribute__((address_space(1))) u32*)g,
                                   (__attribute__((address_space(3))) u32*)l, 16, 0, 0);
}

#define BAR() __builtin_amdgcn_s_barrier()
#define VMCNT4 asm volatile("s_waitcnt vmcnt(4)" ::: "memory")
#define VMCNT0 asm volatile("s_waitcnt vmcnt(0)" ::: "memory")

// ---- U (5120x2048 fp32) -> bf16, scaled by -log2e (sigmoid rows) / +2log2e (u rows)
__global__ void k_cvt_u(const float4* __restrict__ U4, u16* __restrict__ Ubf) {
  int i = blockIdx.x * blockDim.x + threadIdx.x;   // 2,621,440 threads
  int row = i >> 9;                                // 512 float4 per 2048-col row
  float sc = (row < 4096) ? -L2E : (2.0f * L2E);
  float4 v = U4[i];
  u16x4 o = {f2bf(v.x * sc), f2bf(v.y * sc), f2bf(v.z * sc), f2bf(v.w * sc)};
  *(u16x4*)(Ubf + (size_t)i * 4) = o;
}

// ---- chart rows<256: h-half -> chb (bf16, GEMM input); c-half -> chc (f16);
//      also copy rows<256 to out
__global__ void k_cvt_chart(const float* __restrict__ chart,
                            u16* __restrict__ chb, _Float16* __restrict__ chc,
                            float* __restrict__ out) {
  int i = blockIdx.x * blockDim.x + threadIdx.x;   // 2,097,152 threads
  int row = i >> 8;                 // b*256 + op, < 8192
  int k4 = (i & 255) * 4;
  int b = row >> 8, op = row & 255;
  const size_t base = (size_t)(b * CHART_ROWS + op) * 2048;
  const float4 vh = *(const float4*)(chart + base + 1024 + k4);
  const float4 vc = *(const float4*)(chart + base + k4);
  u16x4 oh = {f2bf(vh.x), f2bf(vh.y), f2bf(vh.z), f2bf(vh.w)};
  h4v oc = {(_Float16)vc.x, (_Float16)vc.y, (_Float16)vc.z, (_Float16)vc.w};
  *(u16x4*)(chb + (size_t)row * 1024 + k4) = oh;
  *(h4v*)(chc + (size_t)row * 1024 + k4) = oc;
  *(float4*)(out + base + k4) = vc;          // rows < 256 pass through
  *(float4*)(out + base + 1024 + k4) = vh;   // rows >= 256 written by k_fused
}

// ---- P[bgh][2048 rows][5120] = chb-rows @ U-half (+bias*scale on half0)
// 256x256 tile, BK=64, 8 waves (2Mx4N), 8-phase double-buffered pipeline.
// grid: x = 20 N-tiles, y = nbgh*8 (bgh | mtile). bgh = bg*2 + uhalf.
#define LOAD_A(BUFO, MH) do { \
  _Pragma("unroll") \
  for (int i_ = 0; i_ < 4; ++i_) { \
    a[0][i_] = *(const short8*)(As + (BUFO) + am + (MH)*4096 + i_*1024 + sl0); \
    a[1][i_] = *(const short8*)(As + (BUFO) + am + (MH)*4096 + i_*1024 + sl1); \
  } } while (0)

#define LOAD_B(BUFO, NH, BR) do { \
  _Pragma("unroll") \
  for (int j_ = 0; j_ < 2; ++j_) { \
    BR[0][j_] = *(const short8*)(Bs + (BUFO) + bm + (NH)*2048 + j_*1024 + sl0); \
    BR[1][j_] = *(const short8*)(Bs + (BUFO) + bm + (NH)*2048 + j_*1024 + sl1); \
  } } while (0)

#define MFMA_Q(MH, NH, BR) do { \
  __builtin_amdgcn_s_setprio(1); \
  _Pragma("unroll") \
  for (int kk_ = 0; kk_ < 2; ++kk_) \
    _Pragma("unroll") \
    for (int i_ = 0; i_ < 4; ++i_) \
      _Pragma("unroll") \
      for (int j_ = 0; j_ < 2; ++j_) \
        acc[(MH)*4+i_][(NH)*2+j_] = __builtin_amdgcn_mfma_f32_16x16x32_bf16( \
            a[kk_][i_], BR[kk_][j_], acc[(MH)*4+i_][(NH)*2+j_], 0, 0, 0); \
  __builtin_amdgcn_s_setprio(0); } while (0)

__global__ __launch_bounds__(512, 2) void k_gemm_p(
    const u16* __restrict__ chb, const u16* __restrict__ Ubf,
    const float* __restrict__ bias, _Float16* __restrict__ P, int bgh_base)
{
  __shared__ u16 As[2 * 256 * 64];   // 64 KB: two K-tile buffers (halves stacked)
  __shared__ u16 Bs[2 * 256 * 64];   // 64 KB

  const int tid = threadIdx.x;
  const int wid = tid >> 6, lane = tid & 63;
  const int lane15 = lane & 15, quad = lane >> 4;
  const int wr = wid >> 2, wc = wid & 3;

  // XCD-aware bijective swizzle (nwg % 8 == 0 in both launch shapes)
  const int nwg = gridDim.x * gridDim.y;
  const int flat = blockIdx.y * gridDim.x + blockIdx.x;
  const int swz = (flat & 7) * (nwg >> 3) + (flat >> 3);
  const int bx = swz % 20;                 // N tile (0..19)
  const int by = swz / 20;
  const int bghl = by >> 3;                // local bgh slab in P
  const int bgh = bgh_base + bghl;
  const int bg = bgh >> 1, uhalf = bgh & 1;
  const int mtile = by & 7;

  // staging: half-tile = 128 rows x 64 cols bf16 = 16KB = 2 rounds x 512 thr x 16B
  // chunk idx = rnd*512+tid: row r=idx>>3 (0..127), slot s=idx&7, src chunk c=s^(r&7)
  const u16* aSrc[2]; const u16* bSrc[2]; int dOff[2];
#pragma unroll
  for (int rnd = 0; rnd < 2; ++rnd) {
    int idx = rnd * 512 + tid;
    int r = idx >> 3, s = idx & 7, c = s ^ (r & 7);
    aSrc[rnd] = chb + (size_t)(bg * 2048 + mtile * 256 + r) * 1024 + c * 8;
    bSrc[rnd] = Ubf + (size_t)(bx * 256 + r) * 2048 + uhalf * 1024 + c * 8;
    dOff[rnd] = idx * 8;                   // u16 units
  }
  auto STAGE_A = [&](int buf, int h, int T) {
#pragma unroll
    for (int rnd = 0; rnd < 2; ++rnd)
      async16(aSrc[rnd] + (size_t)h * 131072 + T * 64,
              As + buf * 16384 + h * 8192 + dOff[rnd]);
  };
  auto STAGE_B = [&](int buf, int h, int T) {
#pragma unroll
    for (int rnd = 0; rnd < 2; ++rnd)
      async16(bSrc[rnd] + (size_t)h * 262144 + T * 64,
              Bs + buf * 16384 + h * 8192 + dOff[rnd]);
  };

  // fragment read bases; m&7 == g&7 == lane15&7 (all tile offsets are mult of 8)
  const int sl0 = ((0 * 4 + quad) ^ (lane15 & 7)) * 8;   // kk=0 slot
  const int sl1 = ((1 * 4 + quad) ^ (lane15 & 7)) * 8;   // kk=1 slot
  const int am = (wr * 128 + lane15) * 64;   // + mh*4096 + i*1024
  const int bm = (wc * 64 + lane15) * 64;    // + nh*2048 + j*1024

  f32x4 acc[8][4];
#pragma unroll
  for (int m_ = 0; m_ < 8; ++m_)
#pragma unroll
    for (int n_ = 0; n_ < 4; ++n_) acc[m_][n_] = (f32x4){0.f, 0.f, 0.f, 0.f};

  short8 a[2][4], b0[2][2], b1[2][2];

  // prologue: tile0 fully + tile1 B-halves; tile1 A staged in iter0 p1/p2
  STAGE_B(0, 0, 0); STAGE_B(0, 1, 0); STAGE_A(0, 0, 0); STAGE_A(0, 1, 0);
  STAGE_B(1, 0, 1); STAGE_B(1, 1, 1);
  VMCNT4;                                  // tile0 landed (tile1-B in flight)
  BAR();

  for (int it = 0; it < 8; ++it) {
    const int T1 = 2 * it + 1, T2 = 2 * it + 2, T3 = 2 * it + 3;
    const bool e2 = (T2 < 16), e3 = (T3 < 16);
    // ---- phases 1-4: tile 2it from buf0 ----
    LOAD_A(0, 0); LOAD_B(0, 0, b0);
    STAGE_A(1, 0, T1);
    BAR(); MFMA_Q(0, 0, b0); BAR();

    LOAD_B(0, 1, b1);
    STAGE_A(1, 1, T1);
    BAR(); MFMA_Q(0, 1, b1); BAR();

    LOAD_A(0, 1);
    if (e2) STAGE_B(0, 0, T2);             // buf0 B free after phase 2
    BAR(); MFMA_Q(1, 0, b0); BAR();

    if (e2) STAGE_B(0, 1, T2);
    BAR(); MFMA_Q(1, 1, b1);
    if (e2) { VMCNT4; } else { VMCNT0; }   // tile 2it+1 fully landed
    BAR();
    // ---- phases 5-8: tile 2it+1 from buf1 ----
    LOAD_A(16384, 0); LOAD_B(16384, 0, b0);
    if (e2) STAGE_A(0, 0, T2);             // buf0 A free after phase 3
    BAR(); MFMA_Q(0, 0, b0); BAR();

    LOAD_B(16384, 1, b1);
    if (e2) STAGE_A(0, 1, T2);
    BAR(); MFMA_Q(0, 1, b1); BAR();

    LOAD_A(16384, 1);
    if (e3) STAGE_B(1, 0, T3);             // buf1 B free after phase 6
    BAR(); MFMA_Q(1, 0, b0); BAR();

    if (e3) STAGE_B(1, 1, T3);
    BAR(); MFMA_Q(1, 1, b1);
    if (e3) { VMCNT4; }                    // tile 2it+2 fully landed
    BAR();
  }

  // epilogue: bias (half0 only, pre-scaled) + fp16 store
  float bb[4];
#pragma unroll
  for (int nt = 0; nt < 4; ++nt) {
    int g = bx * 256 + wc * 64 + nt * 16 + lane15;
    float sc = (g < 4096) ? -L2E : (2.0f * L2E);
    bb[nt] = (uhalf == 0) ? bias[g] * sc : 0.f;
  }
  _Float16* Pb = P + ((size_t)bghl * 2048 + mtile * 256 + wr * 128) * 5120
               + bx * 256 + wc * 64;
#pragma unroll
  for (int mt = 0; mt < 8; ++mt)
#pragma unroll
    for (int rg = 0; rg < 4; ++rg) {
      _Float16* pr = Pb + (size_t)(mt * 16 + quad * 4 + rg) * 5120;
#pragma unroll
      for (int nt = 0; nt < 4; ++nt)
        pr[nt * 16 + lane15] = (_Float16)(acc[mt][nt][rg] + bb[nt]);
    }
}

// ---- fused v3: gather-add preact + f16 gates + ONLINE softmax-combine ----
// e = cosine sim in [-1,1] -> exp(e) bounded: softmax without max-subtraction
// is exact. Per wave: 8 a-rows; Sc/Sh accumulate w_a*{c,h} in f32 regs.
// No c/h storage, no barriers in main loop; 4-wave merge through 32KB LDS.
// Column phasing kept: sub in {0,1} covers contiguous cols [sub*512,+512).
__global__ __launch_bounds__(256, 2) void k_fused(
    const _Float16* __restrict__ chc, const _Float16* __restrict__ P,
    const int* __restrict__ ops, const float* __restrict__ eu,
    float* __restrict__ out, int bg0)
{
  __shared__ float rS[4 * 2048];   // 32 KB: [wave][c cols 0..1023 | h cols 1024..2047]
  __shared__ float sS[4];

  const int tid = threadIdx.x;
  const int wave = tid >> 6, lane = tid & 63;
  const int flat = blockIdx.x;
  const int b_local = flat & 7;     // XCD-affine: same-XCD blocks share b
  const int idx = flat >> 3;
  const int step = idx & 127;
  const int bgl = idx >> 7;         // slab index within P
  const int b = (bg0 + bgl) * 8 + b_local;
  const size_t HSLAB = (size_t)2048 * 5120;
  const _Float16* Pl = P + (size_t)(2 * bgl) * HSLAB;

  // energy_u: f32 for unorm, f16 pairs for fdot2
  float uf[2][8];
#pragma unroll
  for (int sub = 0; sub < 2; ++sub) {
    *(float4*)&uf[sub][0] = *(const float4*)(eu + sub * 512 + lane * 8);
    *(float4*)&uf[sub][4] = *(const float4*)(eu + sub * 512 + lane * 8 + 4);
  }
  float part = 0.f;
#pragma unroll
  for (int sub = 0; sub < 2; ++sub)
#pragma unroll
    for (int j = 0; j < 8; ++j) part += uf[sub][j] * uf[sub][j];
#pragma unroll
  for (int m = 1; m < 64; m <<= 1) part += __shfl_xor(part, m, 64);
  const float unorm = fmaxf(sqrtf(part), 1e-8f);
  h2v uu2[2][4];
#pragma unroll
  for (int sub = 0; sub < 2; ++sub)
#pragma unroll
    for (int p = 0; p < 4; ++p)
      uu2[sub][p] = (h2v){(_Float16)uf[sub][2 * p], (_Float16)uf[sub][2 * p + 1]};

  const h2v one2 = {(_Float16)1.0f, (_Float16)1.0f};
  const h2v m2h  = {(_Float16)(-2.0f), (_Float16)(-2.0f)};
  const h2v k2c  = {(_Float16)(2.0f * L2E), (_Float16)(2.0f * L2E)};

  float Sc[2][8], Sh[2][8];
#pragma unroll
  for (int sub = 0; sub < 2; ++sub)
#pragma unroll
    for (int j = 0; j < 8; ++j) { Sc[sub][j] = 0.f; Sh[sub][j] = 0.f; }
  float Ssum = 0.f;

  for (int rr = 0; rr < 8; ++rr) {
    const int a = wave * 8 + rr;
    const long opflat = (((long)step * 32 + b) * 32 + a) * 2;
    const int opL = ops[opflat], opR = ops[opflat + 1];
    const _Float16* PLp = Pl + (size_t)(b_local * 256 + opL) * 5120;
    const _Float16* PRp = Pl + HSLAB + (size_t)(b_local * 256 + opR) * 5120;
    const _Float16* ccL = chc + (size_t)(b * 256 + opL) * 1024;
    const _Float16* ccR = chc + (size_t)(b * 256 + opR) * 1024;
    float dot = 0.f, nn = 0.f;
    h2v cv[2][4], hv[2][4];
#pragma unroll
    for (int sub = 0; sub < 2; ++sub) {
      const int cb = sub * 512 + lane * 8;
      h2v pr2[5][4];
#pragma unroll
      for (int q = 0; q < 5; ++q) {
        h8 t8 = *(const h8*)(PLp + q * 1024 + cb) + *(const h8*)(PRp + q * 1024 + cb);
        *(h8*)&pr2[q][0] = t8;
      }
      h2v cl2[4], cr2[4];
      *(h8*)&cl2[0] = *(const h8*)(ccL + cb);
      *(h8*)&cr2[0] = *(const h8*)(ccR + cb);
#pragma unroll
      for (int p = 0; p < 4; ++p) {
        h2v sI = pk_rcp(one2 + pk_exp2(pr2[0][p]));   // args pre-scaled -log2e
        h2v sL = pk_rcp(one2 + pk_exp2(pr2[1][p]));
        h2v sR = pk_rcp(one2 + pk_exp2(pr2[2][p]));
        h2v sO = pk_rcp(one2 + pk_exp2(pr2[3][p]));
        h2v rU = pk_rcp(one2 + pk_exp2(pr2[4][p]));   // pre-scaled +2log2e
        h2v tU = one2 + m2h * rU;                     // tanh(u)
        h2v c2 = sL * cl2[p] + sR * cr2[p] + sI * tU;
        h2v rC = pk_rcp(one2 + pk_exp2(c2 * k2c));
        h2v tC = one2 + m2h * rC;                     // tanh(c)
        h2v hx = sO * tC;
        cv[sub][p] = c2; hv[sub][p] = hx;
        dot = fdot2a(hx, uu2[sub][p], dot);
        nn  = fdot2a(hx, hx, nn);
      }
    }
#pragma unroll
    for (int m = 1; m < 64; m <<= 1) {
      dot += __shfl_xor(dot, m, 64);
      nn  += __shfl_xor(nn, m, 64);
    }
    const float e = dot / (unorm * fmaxf(sqrtf(nn), 1e-8f));
    const float w = __builtin_amdgcn_exp2f(e * L2E);        // exp(e), e in [-1,1]
    Ssum += w;
#pragma unroll
    for (int sub = 0; sub < 2; ++sub)
#pragma unroll
      for (int p = 0; p < 4; ++p) {
        Sc[sub][2 * p]     += w * (float)cv[sub][p][0];
        Sc[sub][2 * p + 1] += w * (float)cv[sub][p][1];
        Sh[sub][2 * p]     += w * (float)hv[sub][p][0];
        Sh[sub][2 * p + 1] += w * (float)hv[sub][p][1];
      }
  }

  // 4-wave merge through LDS
  if (lane == 0) sS[wave] = Ssum;
#pragma unroll
  for (int sub = 0; sub < 2; ++sub) {
    const int cb = sub * 512 + lane * 8;
    *(float4*)&rS[wave * 2048 + cb]            = *(float4*)&Sc[sub][0];
    *(float4*)&rS[wave * 2048 + cb + 4]        = *(float4*)&Sc[sub][4];
    *(float4*)&rS[wave * 2048 + 1024 + cb]     = *(float4*)&Sh[sub][0];
    *(float4*)&rS[wave * 2048 + 1024 + cb + 4] = *(float4*)&Sh[sub][4];
  }
  __syncthreads();

  const float inv = 1.0f / (sS[0] + sS[1] + sS[2] + sS[3]);
  float* orow = out + ((size_t)b * CHART_ROWS + 256 + step) * 2048;
#pragma unroll
  for (int half = 0; half < 2; ++half) {     // 0: c cols, 1: h cols
#pragma unroll
    for (int sub = 0; sub < 2; ++sub) {
      const int cb = sub * 512 + lane * 8;
      const int off = half * 1024 + cb;
      float s0 = 0.f, s1 = 0.f, s2 = 0.f, s3 = 0.f;
      float s4 = 0.f, s5 = 0.f, s6 = 0.f, s7 = 0.f;
#pragma unroll
      for (int w8 = 0; w8 < 4; ++w8) {
        const float4 v0 = *(const float4*)&rS[w8 * 2048 + off];
        const float4 v1 = *(const float4*)&rS[w8 * 2048 + off + 4];
        s0 += v0.x; s1 += v0.y; s2 += v0.z; s3 += v0.w;
        s4 += v1.x; s5 += v1.y; s6 += v1.z; s7 += v1.w;
      }
      *(float4*)(orow + off)     = make_float4(s0 * inv, s1 * inv, s2 * inv, s3 * inv);
      *(float4*)(orow + off + 4) = make_float4(s4 * inv, s5 * inv, s6 * inv, s7 * inv);
    }
  }
}

extern "C" void kernel_launch(void* const* d_in, const int* in_sizes, int n_in,
                              void* d_out, int out_size, void* d_ws, size_t ws_size,
                              hipStream_t stream) {
  (void)in_sizes; (void)n_in; (void)out_size;
  const float* chart = (const float*)d_in[0];
  const int*   ops   = (const int*)d_in[1];
  // d_in[2] = start_index (256, hard-coded)
  const float* U     = (const float*)d_in[3];
  const float* bias  = (const float*)d_in[4];
  const float* eu    = (const float*)d_in[5];
  float* out = (float*)d_out;
  char* ws = (char*)d_ws;

  u16*      Ubf = (u16*)ws;                       // 20,971,520 B
  u16*      chb = (u16*)(ws + 20971520);          // 16,777,216 B
  _Float16* chc = (_Float16*)(ws + 37748736);     // 16,777,216 B
  _Float16* P   = (_Float16*)(ws + 54525952);     // big: 167,772,160 B (8 slabs)
                                                  // small: 41,943,040 B (2 slabs)
  const size_t SLAB = (size_t)2048 * 5120;        // _Float16 per slab
  const bool big = ws_size >= (size_t)54525952 + 8 * SLAB * 2;

  k_cvt_u<<<10240, 256, 0, stream>>>((const float4*)U, Ubf);
  k_cvt_chart<<<8192, 256, 0, stream>>>(chart, chb, chc, out);

  if (big) {
    // 1280 tiles (20 bx x 8 bgh x 8 mt), 5 exact rounds of 256 blocks
    k_gemm_p<<<dim3(20, 64), 512, 0, stream>>>(chb, Ubf, bias, P, 0);
    // single fused dispatch over all bg (4096 blocks x 256 thr)
    k_fused<<<4096, 256, 0, stream>>>(chc, P, ops, eu, out, 0);
  } else {
    for (int bg = 0; bg < 4; ++bg) {
      k_gemm_p<<<dim3(20, 16), 512, 0, stream>>>(chb, Ubf, bias, P, 2 * bg);
      k_fused<<<1024, 256, 0, stream>>>(chc, P, ops, eu, out, bg);
    }
  }
}